// Round 1
// baseline (225.778 us; speedup 1.0000x reference)
//
#include <hip/hip_runtime.h>
#include <hip/hip_bf16.h>

// Renderer vertex-normals rev11. Math FROZEN from rev8 (passing, absmax = 1 bf16 ulp):
//   cross: c_i = fmaf(a_p, b_q, -pinned(a_q*b_p))  (uniform LHS fusion)
//   norms: (x*x + y*y) + z*z, sqrtf, fmaxf(n,1e-12f), IEEE '/'
//   vertex sum: c = 0..5 sequential per batch accumulator
// Rev11 = batch-INTERLEAVED gather tables (layout only; per-batch math identical).
//   rev10's vertex pass refetched fn 3.7x (272 MB vs 92 MB compulsory): the
//   per-thread bl-loop has no phase barrier, so co-resident blocks smear the
//   working set across all 4 per-XCD fn tables (8.3 MB) in a 4 MB L2.
//   Fix: faces/vti are batch-independent, so pack the 4 batches of each XCD
//   into ONE 64-byte entry per vertex/face:
//     ptsI[xcd][v] = {p(b0,v), p(b1,v), p(b2,v), p(b3,v)}   (4 x float4 = 64 B)
//     fnI [xcd][f] = {n(b0,f), n(b1,f), n(b2,f), n(b3,f)}   (4 x float4 = 64 B)
//   Every random gather is now ONE fully-utilized aligned 64-B line serving
//   all 4 batches: gather count /4 in both passes, line utilization 16/64 ->
//   64/64, and L2 drift no longer costs anything. Streaming reads + final
//   stores are nontemporal so they don't evict gather lines.
// bs=32, V=65536, F=130050, C=6.

#define XCDS 8
#define BPX  4   // batches per XCD; fast path requires bs == XCDS*BPX == 32

__device__ __forceinline__ float mulf_pin(float a, float b) {
  float t = a * b;
  asm("" : "+v"(t));   // pin: separately-rounded f32 product, cannot re-fuse
  return t;
}

__device__ __forceinline__ float3 cross_lhs(float ax, float ay, float az,
                                            float bx, float by, float bz) {
  float cx = __builtin_fmaf(ay, bz, -mulf_pin(az, by));
  float cy = __builtin_fmaf(az, bx, -mulf_pin(ax, bz));
  float cz = __builtin_fmaf(ax, by, -mulf_pin(ay, bx));
  return make_float3(cx, cy, cz);
}

// ---------------- Kernel A: batch-interleaved point pack -------------------
// Thread (xcd, v) writes 64 B contiguous: the 4 batches' float4 points.
// Grid %XCDS mapping puts the writes in the SAME XCD's L2 that kernel B
// gathers from.
__global__ __launch_bounds__(256) void rend11_pack(
    const float* __restrict__ points,   // (bs, 3, V)
    float4*      __restrict__ ptsI,     // (XCDS, V, BPX)
    int V) {
  int xcd = blockIdx.x % XCDS;
  int seq = blockIdx.x / XCDS;
  int v   = seq * 256 + threadIdx.x;
  size_t base = ((size_t)xcd * V + v) * BPX;
#pragma unroll
  for (int bl = 0; bl < BPX; ++bl) {
    int b = xcd * BPX + bl;
    const float* pb = points + (size_t)b * 3 * V;
    float x = __builtin_nontemporal_load(pb + v);
    float y = __builtin_nontemporal_load(pb + V + v);
    float z = __builtin_nontemporal_load(pb + 2 * V + v);
    ptsI[base + bl] = make_float4(x, y, z, 0.0f);
  }
}

// ---------------- Kernel B: face normals, interleaved gather ---------------
// Thread (xcd, f): 3 x 64-B gathers (one per corner, covers all 4 batches),
// 4x frozen cross/normalize, one 64-B contiguous write.
__global__ __launch_bounds__(256) void rend11_face(
    const float4* __restrict__ ptsI,    // (XCDS, V, BPX)
    const int*    __restrict__ faces,   // (F, 3)
    float4*       __restrict__ fnI,     // (XCDS, F, BPX)
    int F, int V) {
  int xcd = blockIdx.x % XCDS;
  int fb  = blockIdx.x / XCDS;
  int f   = fb * 256 + threadIdx.x;
  if (f >= F) return;

  int i0 = __builtin_nontemporal_load(faces + 3 * f + 0);
  int i1 = __builtin_nontemporal_load(faces + 3 * f + 1);
  int i2 = __builtin_nontemporal_load(faces + 3 * f + 2);

  const float4* P0 = ptsI + ((size_t)xcd * V + i0) * BPX;
  const float4* P1 = ptsI + ((size_t)xcd * V + i1) * BPX;
  const float4* P2 = ptsI + ((size_t)xcd * V + i2) * BPX;
  float4* o4 = fnI + ((size_t)xcd * F + f) * BPX;

#pragma unroll
  for (int bl = 0; bl < BPX; ++bl) {
    float4 p0 = P0[bl];
    float4 p1 = P1[bl];
    float4 p2 = P2[bl];

    float ax = p1.x - p0.x, ay = p1.y - p0.y, az = p1.z - p0.z;
    float bx = p2.x - p0.x, by = p2.y - p0.y, bz = p2.z - p0.z;

    float3 c = cross_lhs(ax, ay, az, bx, by, bz);

    float n = sqrtf((c.x * c.x + c.y * c.y) + c.z * c.z);
    float d = fmaxf(n, 1e-12f);

    o4[bl] = make_float4(c.x / d, c.y / d, c.z / d, 0.0f);
  }
}

// ---------------- Kernel C: vertex normals, interleaved gather -------------
// Thread (xcd, v): 6 x 64-B gathers (one per contributing face, covers all
// 4 batches), 4 accumulators, frozen c=0..5 order per accumulator.
__global__ __launch_bounds__(256) void rend11_vertex(
    const float4* __restrict__ fnI,     // (XCDS, F, BPX)
    const int*    __restrict__ vti,     // (V, 6)
    const float*  __restrict__ vtw,     // (V, 6)
    float*        __restrict__ out,     // (bs, V, 3)
    int F, int V) {
  int xcd = blockIdx.x % XCDS;
  int seq = blockIdx.x / XCDS;
  int v   = seq * 256 + threadIdx.x;
  if (v >= V) return;

  const int2*   t2 = (const int2*)(vti + (size_t)v * 6);
  const float2* w2 = (const float2*)(vtw + (size_t)v * 6);
  int2   t01 = t2[0], t23 = t2[1], t45 = t2[2];
  float2 w01 = w2[0], w23 = w2[1], w45 = w2[2];
  int   idx[6] = {t01.x, t01.y, t23.x, t23.y, t45.x, t45.y};
  float wgt[6] = {w01.x, w01.y, w23.x, w23.y, w45.x, w45.y};

  float sx[BPX], sy[BPX], sz[BPX];
#pragma unroll
  for (int bl = 0; bl < BPX; ++bl) { sx[bl] = 0.f; sy[bl] = 0.f; sz[bl] = 0.f; }

#pragma unroll
  for (int c = 0; c < 6; ++c) {          // sequential c-order (frozen)
    const float4* FN = fnI + ((size_t)xcd * F + idx[c]) * BPX;
#pragma unroll
    for (int bl = 0; bl < BPX; ++bl) {
      float4 nr = FN[bl];
      sx[bl] += nr.x * wgt[c];
      sy[bl] += nr.y * wgt[c];
      sz[bl] += nr.z * wgt[c];
    }
  }

#pragma unroll
  for (int bl = 0; bl < BPX; ++bl) {
    int b = xcd * BPX + bl;
    float n = sqrtf((sx[bl] * sx[bl] + sy[bl] * sy[bl]) + sz[bl] * sz[bl]);
    float d = fmaxf(n, 1e-12f);
    size_t o = ((size_t)b * V + v) * 3;
    __builtin_nontemporal_store(sx[bl] / d, out + o + 0);
    __builtin_nontemporal_store(sy[bl] / d, out + o + 1);
    __builtin_nontemporal_store(sz[bl] / d, out + o + 2);
  }
}

// ================= Fallback path (rev8, proven): ===========================
__global__ __launch_bounds__(256) void rend11_face_fb(
    const float* __restrict__ points,
    const int*   __restrict__ faces,
    float4*      __restrict__ fnorm,
    int F, int V) {
  int f = blockIdx.x * blockDim.x + threadIdx.x;
  int b = blockIdx.y;
  if (f >= F) return;

  int i0 = faces[3 * f + 0];
  int i1 = faces[3 * f + 1];
  int i2 = faces[3 * f + 2];

  const float* pb = points + (size_t)b * 3 * V;
  float ax = pb[i1] - pb[i0], ay = pb[V + i1] - pb[V + i0], az = pb[2 * V + i1] - pb[2 * V + i0];
  float bx = pb[i2] - pb[i0], by = pb[V + i2] - pb[V + i0], bz = pb[2 * V + i2] - pb[2 * V + i0];

  float3 c = cross_lhs(ax, ay, az, bx, by, bz);

  float n = sqrtf((c.x * c.x + c.y * c.y) + c.z * c.z);
  float d = fmaxf(n, 1e-12f);

  fnorm[(size_t)b * F + f] = make_float4(c.x / d, c.y / d, c.z / d, 0.0f);
}

__global__ __launch_bounds__(256) void rend11_vertex_fb(
    const float4* __restrict__ fnorm,
    const int*    __restrict__ vti,
    const float*  __restrict__ vtw,
    float*        __restrict__ out,
    int F, int V) {
  int v = blockIdx.x * blockDim.x + threadIdx.x;
  int b = blockIdx.y;
  if (v >= V) return;

  const float4* fb = fnorm + (size_t)b * F;
  float sx = 0.f, sy = 0.f, sz = 0.f;
#pragma unroll
  for (int c = 0; c < 6; ++c) {
    int    idx = vti[v * 6 + c];
    float  w   = vtw[v * 6 + c];
    float4 nr  = fb[idx];
    sx += nr.x * w;
    sy += nr.y * w;
    sz += nr.z * w;
  }
  float n = sqrtf((sx * sx + sy * sy) + sz * sz);
  float d = fmaxf(n, 1e-12f);
  size_t o = ((size_t)b * V + v) * 3;
  out[o + 0] = sx / d;
  out[o + 1] = sy / d;
  out[o + 2] = sz / d;
}

extern "C" void kernel_launch(void* const* d_in, const int* in_sizes, int n_in,
                              void* d_out, int out_size, void* d_ws, size_t ws_size,
                              hipStream_t stream) {
  const float* points = (const float*)d_in[0];
  const int*   faces  = (const int*)d_in[1];
  const int*   vti    = (const int*)d_in[2];
  const float* vtw    = (const float*)d_in[3];
  float*       out    = (float*)d_out;

  const int F  = in_sizes[1] / 3;                       // 130050
  const int V  = in_sizes[2] / 6;                       // 65536
  const int bs = (int)(in_sizes[0] / (3 * (size_t)V));  // 32

  const size_t ptsI_bytes = (size_t)bs * V * sizeof(float4);  // 33.6 MB (same total, permuted)
  const size_t fnI_bytes  = (size_t)bs * F * sizeof(float4);  // 66.6 MB (same total, permuted)

  const bool fast_ok = (ws_size >= ptsI_bytes + fnI_bytes) &&
                       (bs == XCDS * BPX) && (V % 256 == 0);

  if (fast_ok) {
    float4* ptsI = (float4*)d_ws;
    float4* fnI  = (float4*)((char*)d_ws + ptsI_bytes);
    const int fpb = (F + 255) / 256;           // 509 face-blocks per XCD
    const int vpb = V / 256;                   // 256 vertex-blocks per XCD

    rend11_pack<<<dim3(XCDS * vpb), dim3(256), 0, stream>>>(points, ptsI, V);
    rend11_face<<<dim3(XCDS * fpb), dim3(256), 0, stream>>>(ptsI, faces, fnI, F, V);
    rend11_vertex<<<dim3(XCDS * vpb), dim3(256), 0, stream>>>(fnI, vti, vtw, out, F, V);
  } else if (ws_size >= fnI_bytes) {  // rev8 fallback
    float4* fnorm = (float4*)d_ws;
    rend11_face_fb<<<dim3((F + 255) / 256, bs), dim3(256), 0, stream>>>(
        points, faces, fnorm, F, V);
    rend11_vertex_fb<<<dim3((V + 255) / 256, bs), dim3(256), 0, stream>>>(
        fnorm, vti, vtw, out, F, V);
  }
}

// Round 3
// 178.159 us; speedup vs baseline: 1.2673x; 1.2673x over previous
//
#include <hip/hip_runtime.h>
#include <hip/hip_bf16.h>

// Renderer vertex-normals rev12b. Math FROZEN from rev8 (passing, absmax = 1 bf16 ulp):
//   cross: c_i = fmaf(a_p, b_q, -pinned(a_q*b_p))  (uniform LHS fusion)
//   norms: (x*x + y*y) + z*z, sqrtf, fmaxf(n,1e-12f), IEEE '/'
//   vertex sum: c = 0..5 sequential per (v,batch) accumulator
// Rev12 = quad-split lane mapping over rev11's batch-interleaved tables.
//   rev11 face pass: 68 us @ 2.3 TB/s, VALU 11% -> neither BW- nor VALU-bound.
//   Cause: each thread read its own 64-B interleaved entry as 4 serial dwordx4
//   loads -> every wave gather presented 64 DISTINCT lines to the TA
//   (~64 clk/instr, ~27 us of address processing), and per-thread stride-64
//   stores amplified WRITE to 89 MB (vs 66.6 compulsory).
//   Fix: thread g -> (f = g>>2, bl = g&3). A quad's 4 lanes read the 4
//   consecutive float4 of ONE 64-B entry -> coalescer merges to 1 line/quad
//   (16 lines/instr, 4x less TA work; loads/thread 12->3, all independent).
//   Stores land lane-contiguous (full 1-KB lines per instr), marked nt so the
//   8.3 MB/XCD fnI stream doesn't thrash the 4 MB ptsI slice in L2.
//   Per-(f,bl)/(v,bl) FP op order identical to rev11 -> bit-identical output.
// Rev12b: compile fix only — __builtin_nontemporal_store needs a native
//   vector type, not HIP_vector_type<float,4>. Store via ext_vector_type(4).
// bs=32, V=65536, F=130050, C=6.

#define XCDS 8
#define BPX  4   // batches per XCD; fast path requires bs == XCDS*BPX == 32

typedef float f32x4 __attribute__((ext_vector_type(4)));

__device__ __forceinline__ float mulf_pin(float a, float b) {
  float t = a * b;
  asm("" : "+v"(t));   // pin: separately-rounded f32 product, cannot re-fuse
  return t;
}

__device__ __forceinline__ float3 cross_lhs(float ax, float ay, float az,
                                            float bx, float by, float bz) {
  float cx = __builtin_fmaf(ay, bz, -mulf_pin(az, by));
  float cy = __builtin_fmaf(az, bx, -mulf_pin(ax, bz));
  float cz = __builtin_fmaf(ax, by, -mulf_pin(ay, bx));
  return make_float3(cx, cy, cz);
}

__device__ __forceinline__ void nt_store_f4(float4* p, float x, float y,
                                            float z, float w) {
  f32x4 r;
  r[0] = x; r[1] = y; r[2] = z; r[3] = w;
  __builtin_nontemporal_store(r, (f32x4*)p);
}

// ---------------- Kernel A: batch-interleaved point pack -------------------
// Thread (xcd, v) writes 64 B contiguous: the 4 batches' float4 points.
// %XCDS grid mapping keeps the writes in the XCD whose face pass reads them.
__global__ __launch_bounds__(256) void rend12_pack(
    const float* __restrict__ points,   // (bs, 3, V)
    float4*      __restrict__ ptsI,     // (XCDS, V, BPX)
    int V) {
  int xcd = blockIdx.x % XCDS;
  int seq = blockIdx.x / XCDS;
  int v   = seq * 256 + threadIdx.x;
  size_t base = ((size_t)xcd * V + v) * BPX;
#pragma unroll
  for (int bl = 0; bl < BPX; ++bl) {
    int b = xcd * BPX + bl;
    const float* pb = points + (size_t)b * 3 * V;
    float x = __builtin_nontemporal_load(pb + v);
    float y = __builtin_nontemporal_load(pb + V + v);
    float z = __builtin_nontemporal_load(pb + 2 * V + v);
    ptsI[base + bl] = make_float4(x, y, z, 0.0f);
  }
}

// ---------------- Kernel B: face normals, quad-split -----------------------
// Thread g -> (f = g>>2, bl = g&3). 3 gathers x 16 B, quad-merged into full
// 64-B line requests. Store is lane-contiguous (addr = (xcd*F*4+g)*16), nt.
__global__ __launch_bounds__(256) void rend12_face(
    const float4* __restrict__ ptsI,    // (XCDS, V, BPX)
    const int*    __restrict__ faces,   // (F, 3)
    float4*       __restrict__ fnI,     // (XCDS, F, BPX)
    int F, int V) {
  int xcd = blockIdx.x % XCDS;
  int g   = (blockIdx.x / XCDS) * 256 + threadIdx.x;
  int f   = g >> 2;
  int bl  = g & 3;
  if (f >= F) return;

  int i0 = __builtin_nontemporal_load(faces + 3 * f + 0);
  int i1 = __builtin_nontemporal_load(faces + 3 * f + 1);
  int i2 = __builtin_nontemporal_load(faces + 3 * f + 2);

  float4 p0 = ptsI[((size_t)xcd * V + i0) * BPX + bl];
  float4 p1 = ptsI[((size_t)xcd * V + i1) * BPX + bl];
  float4 p2 = ptsI[((size_t)xcd * V + i2) * BPX + bl];

  float ax = p1.x - p0.x, ay = p1.y - p0.y, az = p1.z - p0.z;
  float bx = p2.x - p0.x, by = p2.y - p0.y, bz = p2.z - p0.z;

  float3 c = cross_lhs(ax, ay, az, bx, by, bz);

  float n = sqrtf((c.x * c.x + c.y * c.y) + c.z * c.z);
  float d = fmaxf(n, 1e-12f);

  nt_store_f4(fnI + ((size_t)xcd * F + f) * BPX + bl,
              c.x / d, c.y / d, c.z / d, 0.0f);
}

// ---------------- Kernel C: vertex normals, quad-split ---------------------
// Thread g -> (v = g>>2, bl = g&3). 6 gathers x 16 B, quad-merged to full
// lines. vti/vtw loads broadcast within the quad. c = 0..5 sequential
// accumulation per (v,bl) -- frozen order.
__global__ __launch_bounds__(256) void rend12_vertex(
    const float4* __restrict__ fnI,     // (XCDS, F, BPX)
    const int*    __restrict__ vti,     // (V, 6)
    const float*  __restrict__ vtw,     // (V, 6)
    float*        __restrict__ out,     // (bs, V, 3)
    int F, int V) {
  int xcd = blockIdx.x % XCDS;
  int g   = (blockIdx.x / XCDS) * 256 + threadIdx.x;
  int v   = g >> 2;
  int bl  = g & 3;
  if (v >= V) return;

  const int2*   t2 = (const int2*)(vti + (size_t)v * 6);
  const float2* w2 = (const float2*)(vtw + (size_t)v * 6);
  int2   t01 = t2[0], t23 = t2[1], t45 = t2[2];
  float2 w01 = w2[0], w23 = w2[1], w45 = w2[2];
  int   idx[6] = {t01.x, t01.y, t23.x, t23.y, t45.x, t45.y};
  float wgt[6] = {w01.x, w01.y, w23.x, w23.y, w45.x, w45.y};

  float sx = 0.f, sy = 0.f, sz = 0.f;
#pragma unroll
  for (int c = 0; c < 6; ++c) {          // sequential c-order (frozen)
    float4 nr = fnI[((size_t)xcd * F + idx[c]) * BPX + bl];
    sx += nr.x * wgt[c];
    sy += nr.y * wgt[c];
    sz += nr.z * wgt[c];
  }

  float n = sqrtf((sx * sx + sy * sy) + sz * sz);
  float d = fmaxf(n, 1e-12f);

  int b = xcd * BPX + bl;
  size_t o = ((size_t)b * V + v) * 3;
  __builtin_nontemporal_store(sx / d, out + o + 0);
  __builtin_nontemporal_store(sy / d, out + o + 1);
  __builtin_nontemporal_store(sz / d, out + o + 2);
}

// ================= Fallback path (rev8, proven): ===========================
__global__ __launch_bounds__(256) void rend12_face_fb(
    const float* __restrict__ points,
    const int*   __restrict__ faces,
    float4*      __restrict__ fnorm,
    int F, int V) {
  int f = blockIdx.x * blockDim.x + threadIdx.x;
  int b = blockIdx.y;
  if (f >= F) return;

  int i0 = faces[3 * f + 0];
  int i1 = faces[3 * f + 1];
  int i2 = faces[3 * f + 2];

  const float* pb = points + (size_t)b * 3 * V;
  float ax = pb[i1] - pb[i0], ay = pb[V + i1] - pb[V + i0], az = pb[2 * V + i1] - pb[2 * V + i0];
  float bx = pb[i2] - pb[i0], by = pb[V + i2] - pb[V + i0], bz = pb[2 * V + i2] - pb[2 * V + i0];

  float3 c = cross_lhs(ax, ay, az, bx, by, bz);

  float n = sqrtf((c.x * c.x + c.y * c.y) + c.z * c.z);
  float d = fmaxf(n, 1e-12f);

  fnorm[(size_t)b * F + f] = make_float4(c.x / d, c.y / d, c.z / d, 0.0f);
}

__global__ __launch_bounds__(256) void rend12_vertex_fb(
    const float4* __restrict__ fnorm,
    const int*    __restrict__ vti,
    const float*  __restrict__ vtw,
    float*        __restrict__ out,
    int F, int V) {
  int v = blockIdx.x * blockDim.x + threadIdx.x;
  int b = blockIdx.y;
  if (v >= V) return;

  const float4* fb = fnorm + (size_t)b * F;
  float sx = 0.f, sy = 0.f, sz = 0.f;
#pragma unroll
  for (int c = 0; c < 6; ++c) {
    int    idx = vti[v * 6 + c];
    float  w   = vtw[v * 6 + c];
    float4 nr  = fb[idx];
    sx += nr.x * w;
    sy += nr.y * w;
    sz += nr.z * w;
  }
  float n = sqrtf((sx * sx + sy * sy) + sz * sz);
  float d = fmaxf(n, 1e-12f);
  size_t o = ((size_t)b * V + v) * 3;
  out[o + 0] = sx / d;
  out[o + 1] = sy / d;
  out[o + 2] = sz / d;
}

extern "C" void kernel_launch(void* const* d_in, const int* in_sizes, int n_in,
                              void* d_out, int out_size, void* d_ws, size_t ws_size,
                              hipStream_t stream) {
  const float* points = (const float*)d_in[0];
  const int*   faces  = (const int*)d_in[1];
  const int*   vti    = (const int*)d_in[2];
  const float* vtw    = (const float*)d_in[3];
  float*       out    = (float*)d_out;

  const int F  = in_sizes[1] / 3;                       // 130050
  const int V  = in_sizes[2] / 6;                       // 65536
  const int bs = (int)(in_sizes[0] / (3 * (size_t)V));  // 32

  const size_t ptsI_bytes = (size_t)bs * V * sizeof(float4);  // 33.6 MB
  const size_t fnI_bytes  = (size_t)bs * F * sizeof(float4);  // 66.6 MB

  const bool fast_ok = (ws_size >= ptsI_bytes + fnI_bytes) &&
                       (bs == XCDS * BPX) && (V % 256 == 0);

  if (fast_ok) {
    float4* ptsI = (float4*)d_ws;
    float4* fnI  = (float4*)((char*)d_ws + ptsI_bytes);
    const int vpb = V / 256;                        // 256 pack-blocks per XCD
    const int fqb = (F * BPX + 255) / 256;          // 2033 face-quad blocks per XCD
    const int vqb = (V * BPX) / 256;                // 1024 vertex-quad blocks per XCD

    rend12_pack<<<dim3(XCDS * vpb), dim3(256), 0, stream>>>(points, ptsI, V);
    rend12_face<<<dim3(XCDS * fqb), dim3(256), 0, stream>>>(ptsI, faces, fnI, F, V);
    rend12_vertex<<<dim3(XCDS * vqb), dim3(256), 0, stream>>>(fnI, vti, vtw, out, F, V);
  } else if (ws_size >= fnI_bytes) {  // rev8 fallback
    float4* fnorm = (float4*)d_ws;
    rend12_face_fb<<<dim3((F + 255) / 256, bs), dim3(256), 0, stream>>>(
        points, faces, fnorm, F, V);
    rend12_vertex_fb<<<dim3((V + 255) / 256, bs), dim3(256), 0, stream>>>(
        fnorm, vti, vtw, out, F, V);
  }
}

// Round 4
// 165.314 us; speedup vs baseline: 1.3658x; 1.0777x over previous
//
#include <hip/hip_runtime.h>
#include <hip/hip_bf16.h>

// Renderer vertex-normals rev13. Math FROZEN from rev8 (passing, absmax = 1 bf16 ulp):
//   cross: c_i = fmaf(a_p, b_q, -pinned(a_q*b_p))  (uniform LHS fusion)
//   norms: (x*x + y*y) + z*z, sqrtf, fmaxf(n,1e-12f), IEEE '/'
//   vertex sum: c = 0..5 sequential per (v,batch) accumulator
// Rev12 (kept): batch-interleaved tables + quad-split lane mapping.
//   face FETCH = 33.5 MB = compulsory (ptsI read once; L2 serves ~6x reuse),
//   WRITE = 65 MB = compulsory. But face = 44 us @ 2.27 TB/s, VALU 22%,
//   occupancy 62% -> latency-bound: only 3 outstanding gathers/thread after a
//   dependent index load (~15 in-flight/SIMD vs ~1.3K-cycle chains).
// Rev13 = MLP doubling, layout/scheduling only:
//   FACE: FPT=2 faces per thread (f0=q, f1=q+F/2). 6 index loads then 6
//   INDEPENDENT quad-merged gathers in flight, then two frozen compute+store
//   sequences. ~50 VGPR, stays under the 64-VGPR occupancy cliff ->
//   in-flight gathers/SIMD ~3x. Stores stay wave-contiguous full lines.
//   PACK: quad-split too (thread g -> v=g>>2, bl=g&3): 3 coalesced loads +
//   1 fully-contiguous 16-B/lane store (4 mem instrs vs 16).
//   VERTEX: unchanged from rev12 (already 6 independent gathers @ VGPR 36).
// bs=32, V=65536, F=130050, C=6.

#define XCDS 8
#define BPX  4   // batches per XCD; fast path requires bs == XCDS*BPX == 32
#define FPT  2   // faces per thread in the face pass (requires F % FPT == 0)

typedef float f32x4 __attribute__((ext_vector_type(4)));

__device__ __forceinline__ float mulf_pin(float a, float b) {
  float t = a * b;
  asm("" : "+v"(t));   // pin: separately-rounded f32 product, cannot re-fuse
  return t;
}

__device__ __forceinline__ float3 cross_lhs(float ax, float ay, float az,
                                            float bx, float by, float bz) {
  float cx = __builtin_fmaf(ay, bz, -mulf_pin(az, by));
  float cy = __builtin_fmaf(az, bx, -mulf_pin(ax, bz));
  float cz = __builtin_fmaf(ax, by, -mulf_pin(ay, bx));
  return make_float3(cx, cy, cz);
}

__device__ __forceinline__ void nt_store_f4(float4* p, float x, float y,
                                            float z, float w) {
  f32x4 r;
  r[0] = x; r[1] = y; r[2] = z; r[3] = w;
  __builtin_nontemporal_store(r, (f32x4*)p);
}

// ---------------- Kernel A: batch-interleaved point pack, quad-split -------
// Thread g -> (v = g>>2, bl = g&3). 3 coalesced nt loads (4 contiguous 64-B
// runs per wave instr), one fully-contiguous regular store (allocates in the
// XCD's L2 that kernel B gathers from).
__global__ __launch_bounds__(256) void rend13_pack(
    const float* __restrict__ points,   // (bs, 3, V)
    float4*      __restrict__ ptsI,     // (XCDS, V, BPX)
    int V) {
  int xcd = blockIdx.x % XCDS;
  int g   = (blockIdx.x / XCDS) * 256 + threadIdx.x;
  int v   = g >> 2;
  int bl  = g & 3;
  int b   = xcd * BPX + bl;
  const float* pb = points + (size_t)b * 3 * V;
  float x = __builtin_nontemporal_load(pb + v);
  float y = __builtin_nontemporal_load(pb + V + v);
  float z = __builtin_nontemporal_load(pb + 2 * V + v);
  ptsI[((size_t)xcd * V + v) * BPX + bl] = make_float4(x, y, z, 0.0f);
}

// ---------------- Kernel B: face normals, quad-split, FPT=2 ----------------
// Thread (q, bl) handles f0 = q and f1 = q + Q (Q = F/FPT): 6 index loads,
// then 6 independent quad-merged 64-B gathers in flight, then two frozen
// compute+store sequences. Per-face math identical to rev12 -> bit-identical.
__global__ __launch_bounds__(256) void rend13_face(
    const float4* __restrict__ ptsI,    // (XCDS, V, BPX)
    const int*    __restrict__ faces,   // (F, 3)
    float4*       __restrict__ fnI,     // (XCDS, F, BPX)
    int F, int V, int Q) {
  int xcd = blockIdx.x % XCDS;
  int g   = (blockIdx.x / XCDS) * 256 + threadIdx.x;
  int q   = g >> 2;
  int bl  = g & 3;
  if (q >= Q) return;

  int f0 = q;
  int f1 = q + Q;

  int a0 = __builtin_nontemporal_load(faces + 3 * f0 + 0);
  int a1 = __builtin_nontemporal_load(faces + 3 * f0 + 1);
  int a2 = __builtin_nontemporal_load(faces + 3 * f0 + 2);
  int b0 = __builtin_nontemporal_load(faces + 3 * f1 + 0);
  int b1 = __builtin_nontemporal_load(faces + 3 * f1 + 1);
  int b2 = __builtin_nontemporal_load(faces + 3 * f1 + 2);

  const float4* P = ptsI + (size_t)xcd * V * BPX;
  float4 pa0 = P[(size_t)a0 * BPX + bl];
  float4 pa1 = P[(size_t)a1 * BPX + bl];
  float4 pa2 = P[(size_t)a2 * BPX + bl];
  float4 pb0 = P[(size_t)b0 * BPX + bl];
  float4 pb1 = P[(size_t)b1 * BPX + bl];
  float4 pb2 = P[(size_t)b2 * BPX + bl];

  {
    float ax = pa1.x - pa0.x, ay = pa1.y - pa0.y, az = pa1.z - pa0.z;
    float bx = pa2.x - pa0.x, by = pa2.y - pa0.y, bz = pa2.z - pa0.z;
    float3 c = cross_lhs(ax, ay, az, bx, by, bz);
    float n = sqrtf((c.x * c.x + c.y * c.y) + c.z * c.z);
    float d = fmaxf(n, 1e-12f);
    nt_store_f4(fnI + ((size_t)xcd * F + f0) * BPX + bl,
                c.x / d, c.y / d, c.z / d, 0.0f);
  }
  {
    float ax = pb1.x - pb0.x, ay = pb1.y - pb0.y, az = pb1.z - pb0.z;
    float bx = pb2.x - pb0.x, by = pb2.y - pb0.y, bz = pb2.z - pb0.z;
    float3 c = cross_lhs(ax, ay, az, bx, by, bz);
    float n = sqrtf((c.x * c.x + c.y * c.y) + c.z * c.z);
    float d = fmaxf(n, 1e-12f);
    nt_store_f4(fnI + ((size_t)xcd * F + f1) * BPX + bl,
                c.x / d, c.y / d, c.z / d, 0.0f);
  }
}

// ---------------- Kernel C: vertex normals, quad-split (rev12, unchanged) --
__global__ __launch_bounds__(256) void rend13_vertex(
    const float4* __restrict__ fnI,     // (XCDS, F, BPX)
    const int*    __restrict__ vti,     // (V, 6)
    const float*  __restrict__ vtw,     // (V, 6)
    float*        __restrict__ out,     // (bs, V, 3)
    int F, int V) {
  int xcd = blockIdx.x % XCDS;
  int g   = (blockIdx.x / XCDS) * 256 + threadIdx.x;
  int v   = g >> 2;
  int bl  = g & 3;
  if (v >= V) return;

  const int2*   t2 = (const int2*)(vti + (size_t)v * 6);
  const float2* w2 = (const float2*)(vtw + (size_t)v * 6);
  int2   t01 = t2[0], t23 = t2[1], t45 = t2[2];
  float2 w01 = w2[0], w23 = w2[1], w45 = w2[2];
  int   idx[6] = {t01.x, t01.y, t23.x, t23.y, t45.x, t45.y};
  float wgt[6] = {w01.x, w01.y, w23.x, w23.y, w45.x, w45.y};

  float sx = 0.f, sy = 0.f, sz = 0.f;
#pragma unroll
  for (int c = 0; c < 6; ++c) {          // sequential c-order (frozen)
    float4 nr = fnI[((size_t)xcd * F + idx[c]) * BPX + bl];
    sx += nr.x * wgt[c];
    sy += nr.y * wgt[c];
    sz += nr.z * wgt[c];
  }

  float n = sqrtf((sx * sx + sy * sy) + sz * sz);
  float d = fmaxf(n, 1e-12f);

  int b = xcd * BPX + bl;
  size_t o = ((size_t)b * V + v) * 3;
  __builtin_nontemporal_store(sx / d, out + o + 0);
  __builtin_nontemporal_store(sy / d, out + o + 1);
  __builtin_nontemporal_store(sz / d, out + o + 2);
}

// ================= Fallback path (rev8, proven): ===========================
__global__ __launch_bounds__(256) void rend13_face_fb(
    const float* __restrict__ points,
    const int*   __restrict__ faces,
    float4*      __restrict__ fnorm,
    int F, int V) {
  int f = blockIdx.x * blockDim.x + threadIdx.x;
  int b = blockIdx.y;
  if (f >= F) return;

  int i0 = faces[3 * f + 0];
  int i1 = faces[3 * f + 1];
  int i2 = faces[3 * f + 2];

  const float* pb = points + (size_t)b * 3 * V;
  float ax = pb[i1] - pb[i0], ay = pb[V + i1] - pb[V + i0], az = pb[2 * V + i1] - pb[2 * V + i0];
  float bx = pb[i2] - pb[i0], by = pb[V + i2] - pb[V + i0], bz = pb[2 * V + i2] - pb[2 * V + i0];

  float3 c = cross_lhs(ax, ay, az, bx, by, bz);

  float n = sqrtf((c.x * c.x + c.y * c.y) + c.z * c.z);
  float d = fmaxf(n, 1e-12f);

  fnorm[(size_t)b * F + f] = make_float4(c.x / d, c.y / d, c.z / d, 0.0f);
}

__global__ __launch_bounds__(256) void rend13_vertex_fb(
    const float4* __restrict__ fnorm,
    const int*    __restrict__ vti,
    const float*  __restrict__ vtw,
    float*        __restrict__ out,
    int F, int V) {
  int v = blockIdx.x * blockDim.x + threadIdx.x;
  int b = blockIdx.y;
  if (v >= V) return;

  const float4* fb = fnorm + (size_t)b * F;
  float sx = 0.f, sy = 0.f, sz = 0.f;
#pragma unroll
  for (int c = 0; c < 6; ++c) {
    int    idx = vti[v * 6 + c];
    float  w   = vtw[v * 6 + c];
    float4 nr  = fb[idx];
    sx += nr.x * w;
    sy += nr.y * w;
    sz += nr.z * w;
  }
  float n = sqrtf((sx * sx + sy * sy) + sz * sz);
  float d = fmaxf(n, 1e-12f);
  size_t o = ((size_t)b * V + v) * 3;
  out[o + 0] = sx / d;
  out[o + 1] = sy / d;
  out[o + 2] = sz / d;
}

extern "C" void kernel_launch(void* const* d_in, const int* in_sizes, int n_in,
                              void* d_out, int out_size, void* d_ws, size_t ws_size,
                              hipStream_t stream) {
  const float* points = (const float*)d_in[0];
  const int*   faces  = (const int*)d_in[1];
  const int*   vti    = (const int*)d_in[2];
  const float* vtw    = (const float*)d_in[3];
  float*       out    = (float*)d_out;

  const int F  = in_sizes[1] / 3;                       // 130050
  const int V  = in_sizes[2] / 6;                       // 65536
  const int bs = (int)(in_sizes[0] / (3 * (size_t)V));  // 32

  const size_t ptsI_bytes = (size_t)bs * V * sizeof(float4);  // 33.6 MB
  const size_t fnI_bytes  = (size_t)bs * F * sizeof(float4);  // 66.6 MB

  const bool fast_ok = (ws_size >= ptsI_bytes + fnI_bytes) &&
                       (bs == XCDS * BPX) && (V % 256 == 0) && (F % FPT == 0);

  if (fast_ok) {
    float4* ptsI = (float4*)d_ws;
    float4* fnI  = (float4*)((char*)d_ws + ptsI_bytes);
    const int Q   = F / FPT;                        // 65025 face-pairs
    const int ppb = (V * BPX) / 256;                // 1024 pack-blocks per XCD
    const int fqb = (Q * 4 + 255) / 256;            // 1017 face-quad blocks per XCD
    const int vqb = (V * BPX) / 256;                // 1024 vertex-quad blocks per XCD

    rend13_pack<<<dim3(XCDS * ppb), dim3(256), 0, stream>>>(points, ptsI, V);
    rend13_face<<<dim3(XCDS * fqb), dim3(256), 0, stream>>>(ptsI, faces, fnI, F, V, Q);
    rend13_vertex<<<dim3(XCDS * vqb), dim3(256), 0, stream>>>(fnI, vti, vtw, out, F, V);
  } else if (ws_size >= fnI_bytes) {  // rev8 fallback
    float4* fnorm = (float4*)d_ws;
    rend13_face_fb<<<dim3((F + 255) / 256, bs), dim3(256), 0, stream>>>(
        points, faces, fnorm, F, V);
    rend13_vertex_fb<<<dim3((V + 255) / 256, bs), dim3(256), 0, stream>>>(
        fnorm, vti, vtw, out, F, V);
  }
}